// Round 4
// baseline (283.645 us; speedup 1.0000x reference)
//
#include <hip/hip_runtime.h>
#include <hip/hip_bf16.h>

typedef __attribute__((ext_vector_type(8))) short short8;   // 8 bf16 = 4 VGPRs (MFMA A/B frag)
typedef __attribute__((ext_vector_type(4))) short short4v;  // 4 bf16 = 8 B
typedef __attribute__((ext_vector_type(4))) float floatx4;  // MFMA C/D frag

#define MFMA(a, b, c) __builtin_amdgcn_mfma_f32_16x16x32_bf16((a), (b), (c), 0, 0, 0)

// fp32 -> bf16, round-to-nearest-even (bit trick; inputs are finite)
__device__ __forceinline__ short f2bf(float f) {
    unsigned u = __float_as_uint(f);
    u += 0x7fffu + ((u >> 16) & 1u);
    return (short)(u >> 16);
}

__device__ __forceinline__ short8 pack_bf16(floatx4 a, floatx4 b) {
    short8 r;
    r[0] = f2bf(a.x); r[1] = f2bf(a.y); r[2] = f2bf(a.z); r[3] = f2bf(a.w);
    r[4] = f2bf(b.x); r[5] = f2bf(b.y); r[6] = f2bf(b.z); r[7] = f2bf(b.w);
    return r;
}

// ---------------------------------------------------------------------------
// Cayley via Neumann/Horner series on one block (256 threads, 4 waves).
// (unchanged — negligible runtime)
// ---------------------------------------------------------------------------
__device__ void cayley64(const float* __restrict__ X, const float* __restrict__ dg,
                         short* outArr, int mode,
                         short* Brow, float* Bcol, short* T0, short* T1, int tid)
{
    int i0 = (tid * 16) >> 6;
    int j0 = (tid * 16) & 63;
#pragma unroll
    for (int s = 0; s < 16; ++s) {
        int i = i0, j = j0 + s;
        float b = 0.f;
        if (i > j)      b =  0.5f * X[i * 64 + j];
        else if (i < j) b = -0.5f * X[j * 64 + i];
        Brow[i * 72 + j] = f2bf(b);
        Bcol[j * 68 + i] = b;
        T0[j * 72 + i]   = f2bf(b);
    }
    __syncthreads();

    int lane = tid & 63, w = tid >> 6, m = lane & 15, q = lane >> 4;
    int arow = (w * 16 + m) * 72;
    short8 a0 = *(const short8*)&Brow[arow + q * 8];
    short8 a1 = *(const short8*)&Brow[arow + 32 + q * 8];

    short* Tbuf[2] = {T0, T1};
    int cur = 0;
    const int NSTEP = 6;
    for (int step = 0; step < NSTEP; ++step) {
        bool last = (step == NSTEP - 1);
        short* Tr = Tbuf[cur];
        short* Tw = Tbuf[cur ^ 1];
#pragma unroll
        for (int c = 0; c < 4; ++c) {
            int coff = c * 16 + m;
            short8 b0 = *(const short8*)&Tr[coff * 72 + q * 8];
            short8 b1 = *(const short8*)&Tr[coff * 72 + 32 + q * 8];
            floatx4 acc = {0.f, 0.f, 0.f, 0.f};
            acc = MFMA(a0, b0, acc);
            acc = MFMA(a1, b1, acc);
            int row0 = w * 16 + q * 4;
            floatx4 badd = *(const floatx4*)&Bcol[coff * 68 + row0];
            floatx4 t = badd + acc;                 // T_new = B + B*T_old
            if (!last) {
                short4v pk = { f2bf(t.x), f2bf(t.y), f2bf(t.z), f2bf(t.w) };
                *(short4v*)&Tw[coff * 72 + row0] = pk;
            } else {
                int col = coff;
                floatx4 cv;
                cv.x = ((row0 + 0) == col ? 1.f : 0.f) + 2.f * t.x;
                cv.y = ((row0 + 1) == col ? 1.f : 0.f) + 2.f * t.y;
                cv.z = ((row0 + 2) == col ? 1.f : 0.f) + 2.f * t.z;
                cv.w = ((row0 + 3) == col ? 1.f : 0.f) + 2.f * t.w;
                if (mode == 0) {
                    outArr[(row0 + 0) * 72 + col] = f2bf(cv.x);
                    outArr[(row0 + 1) * 72 + col] = f2bf(cv.y);
                    outArr[(row0 + 2) * 72 + col] = f2bf(cv.z);
                    outArr[(row0 + 3) * 72 + col] = f2bf(cv.w);
                } else {
                    floatx4 dv = *(const floatx4*)&dg[row0];
                    short4v pk = { f2bf(cv.x * dv.x), f2bf(cv.y * dv.y),
                                   f2bf(cv.z * dv.z), f2bf(cv.w * dv.w) };
                    *(short4v*)&outArr[col * 72 + row0] = pk;
                }
            }
        }
        __syncthreads();
        cur ^= 1;
    }
}

// ---------------------------------------------------------------------------
// k_prep: 2 blocks. Block 0 -> m_left^T, block 1 -> m_right^T (bf16 row-major)
// ---------------------------------------------------------------------------
__global__ __launch_bounds__(256) void k_prep(
        const float* __restrict__ u_l, const float* __restrict__ v_l, const float* __restrict__ dg_l,
        const float* __restrict__ u_r, const float* __restrict__ v_r, const float* __restrict__ dg_r,
        short* __restrict__ wsOut)
{
    __shared__ __align__(16) short Brow[64 * 72];
    __shared__ __align__(16) float Bcol[64 * 68];
    __shared__ __align__(16) short T0[64 * 72];
    __shared__ __align__(16) short T1[64 * 72];
    __shared__ __align__(16) short CvA[64 * 72];
    __shared__ __align__(16) short CuB[64 * 72];

    int tid = threadIdx.x;
    const float* U  = (blockIdx.x == 0) ? u_l  : u_r;
    const float* V  = (blockIdx.x == 0) ? v_l  : v_r;
    const float* DG = (blockIdx.x == 0) ? dg_l : dg_r;
    short* outT = wsOut + blockIdx.x * 4096;

    cayley64(V, DG, CvA, 1, Brow, Bcol, T0, T1, tid);
    __syncthreads();
    cayley64(U, DG, CuB, 0, Brow, Bcol, T0, T1, tid);
    __syncthreads();

    int lane = tid & 63, w = tid >> 6, m = lane & 15, q = lane >> 4;
    int arow = (w * 16 + m) * 72;
    short8 a0 = *(const short8*)&CvA[arow + q * 8];
    short8 a1 = *(const short8*)&CvA[arow + 32 + q * 8];
#pragma unroll
    for (int c = 0; c < 4; ++c) {
        short8 b0 = *(const short8*)&CuB[(c * 16 + m) * 72 + q * 8];
        short8 b1 = *(const short8*)&CuB[(c * 16 + m) * 72 + 32 + q * 8];
        floatx4 acc = {0.f, 0.f, 0.f, 0.f};
        acc = MFMA(a0, b0, acc);
        acc = MFMA(a1, b1, acc);
        int row0 = w * 16 + q * 4, col = c * 16 + m;
        outT[(row0 + 0) * 64 + col] = f2bf(acc.x);
        outT[(row0 + 1) * 64 + col] = f2bf(acc.y);
        outT[(row0 + 2) * 64 + col] = f2bf(acc.z);
        outT[(row0 + 3) * 64 + col] = f2bf(acc.w);
    }
}

// ---------------------------------------------------------------------------
// k_main v7: out_n = P @ (x_n * dscale) @ Q
//   Evidence from v3/v4/v5spill/v6: HBM BW tracks WAVES/CU, not nominal
//   outstanding bytes (per-wave concurrency cap).  So: maximize resident
//   waves with always-open load windows.
//   - 4-wave blocks, grid 768 -> 3 blocks/CU (LDS 49KB), 12 waves/CU all
//     resident; each wave handles matrices n = wgid + k*3072 (<=3).
//   - x loaded to REGISTERS, 2 chunks (8KB/wave) in flight at every consume
//     point, incl. across matrix boundaries (next-matrix c0/c1 issued before
//     phase B).  NO other VMEM in the loop:
//   - dscale staged ONCE to padded LDS (lgkmcnt, invisible to vmcnt FIFO) --
//     v4's fatal flaw was per-chunk dsc global loads draining the prefetch.
//   - P/Q frags pinned in VGPRs; S^T per-wave swizzled LDS (v6-validated);
//     phase B operand-swapped -> plain dwordx4 stores (v6-validated).
//   - launch_bounds(256,3): VGPR <= 170 for 3 waves/SIMD.
//   Numerics bit-identical to v6 (same values, same MFMA order).
// ---------------------------------------------------------------------------
__global__ __launch_bounds__(256, 3) void k_main(
        const float* __restrict__ x, const float* __restrict__ dsc,
        const short* __restrict__ mLT, const short* __restrict__ mRT,
        float* __restrict__ out, int N)
{
    __shared__ __align__(16) char  STb[4][8192];   // per-wave swizzled S^T
    __shared__ __align__(16) float dsl[64 * 68];   // dscale, +4 float row pad

    const int tid = threadIdx.x;
    const int w = tid >> 6, lane = tid & 63, m = lane & 15, q = lane >> 4;
    const int s8 = m & 7;
    char* st = STb[w];

    // ---- stage dscale to LDS (once; only barrier in the kernel)
    {
        int row = tid >> 2, c4 = (tid & 3) * 16;
        const float* g = dsc + row * 64 + c4;
        float* l = dsl + row * 68 + c4;
        *(floatx4*)&l[0]  = *(const floatx4*)&g[0];
        *(floatx4*)&l[4]  = *(const floatx4*)&g[4];
        *(floatx4*)&l[8]  = *(const floatx4*)&g[8];
        *(floatx4*)&l[12] = *(const floatx4*)&g[12];
    }

    // P-row frags (B-operand of P^T in phase B) and Q^T frags
    short8 pf[4][2], qf[4][2];
#pragma unroll
    for (int r = 0; r < 4; ++r) {
        pf[r][0] = *(const short8*)&mLT[(r * 16 + m) * 64 + q * 8];
        pf[r][1] = *(const short8*)&mLT[(r * 16 + m) * 64 + 32 + q * 8];
        qf[r][0] = *(const short8*)&mRT[(r * 16 + m) * 64 + q * 8];
        qf[r][1] = *(const short8*)&mRT[(r * 16 + m) * 64 + 32 + q * 8];
    }
    __syncthreads();

    const long stride = (long)gridDim.x * 4;        // matrices per generation
    const long wgid = (long)blockIdx.x * 4 + w;
    if (wgid >= N) return;

    const int loff = m * 64 + q * 8;                // lane offset within chunk

// load chunk j of the matrix at float-pointer p into 4 named floatx4 regs
#define LDCHUNK(p, j, r0, r1, r2, r3) do {                       \
        const float* cp_ = (p) + (j) * 1024;                     \
        r0 = *(const floatx4*)&cp_[0];                           \
        r1 = *(const floatx4*)&cp_[4];                           \
        r2 = *(const floatx4*)&cp_[32];                          \
        r3 = *(const floatx4*)&cp_[36];                          \
        asm volatile("" ::: "memory");  /* keep issue point */   \
    } while (0)

// phase A for row-tile rt using chunk regs: S row-tile -> swizzled S^T slice
#define PHASE_A(rt, r0, r1, r2, r3) do {                                      \
        const float* dp_ = &dsl[((rt) * 16 + m) * 68 + q * 8];                \
        floatx4 d0_ = *(const floatx4*)&dp_[0];                               \
        floatx4 d1_ = *(const floatx4*)&dp_[4];                               \
        floatx4 d2_ = *(const floatx4*)&dp_[32];                              \
        floatx4 d3_ = *(const floatx4*)&dp_[36];                              \
        short8 a0_ = pack_bf16(r0 * d0_, r1 * d1_);   /* k 0..31  */          \
        short8 a1_ = pack_bf16(r2 * d2_, r3 * d3_);   /* k 32..63 */          \
        _Pragma("unroll")                                                     \
        for (int c_ = 0; c_ < 4; ++c_) {                                      \
            floatx4 s_ = {0.f, 0.f, 0.f, 0.f};                                \
            s_ = MFMA(a0_, qf[c_][0], s_);                                    \
            s_ = MFMA(a1_, qf[c_][1], s_);                                    \
            short4v pk_ = { f2bf(s_.x), f2bf(s_.y), f2bf(s_.z), f2bf(s_.w) }; \
            *(short4v*)&st[(c_ * 16 + m) * 128 +                              \
                (((2 * (rt) + (q >> 1)) ^ s8) << 4) + (q & 1) * 8] = pk_;     \
        }                                                                     \
    } while (0)

    long n = wgid;
    const float* xp = x + n * 4096 + loff;

    // prologue: chunks 0,1 of first matrix in flight
    floatx4 A0, A1, A2, A3, B0, B1, B2, B3, C0, C1, C2, C3, D0, D1, D2, D3;
    LDCHUNK(xp, 0, A0, A1, A2, A3);
    LDCHUNK(xp, 1, B0, B1, B2, B3);

    for (;;) {
        const long nn = n + stride;
        const bool hasnext = (nn < N);              // wave-uniform

        LDCHUNK(xp, 2, C0, C1, C2, C3);
        PHASE_A(0, A0, A1, A2, A3);                 // waits A; B,C in flight
        LDCHUNK(xp, 3, D0, D1, D2, D3);
        PHASE_A(1, B0, B1, B2, B3);                 // waits B; C,D in flight
        if (hasnext) {
            const float* xn = xp + stride * 4096;
            LDCHUNK(xn, 0, A0, A1, A2, A3);         // next-matrix c0
            PHASE_A(2, C0, C1, C2, C3);             // waits C; D,A' in flight
            LDCHUNK(xn, 1, B0, B1, B2, B3);         // next-matrix c1
            PHASE_A(3, D0, D1, D2, D3);             // waits D; A',B' in flight
        } else {
            PHASE_A(2, C0, C1, C2, C3);
            PHASE_A(3, D0, D1, D2, D3);
        }

        // ---- phase B: O^T = S^T @ P^T (operand-swapped) -> dwordx4 stores
        float* op = out + (size_t)n * 4096;
#pragma unroll
        for (int c2 = 0; c2 < 4; ++c2) {
            const int rowb = (c2 * 16 + m) * 128;
            short8 sb0 = *(const short8*)&st[rowb + ((q       ^ s8) << 4)];
            short8 sb1 = *(const short8*)&st[rowb + (((4 + q) ^ s8) << 4)];
#pragma unroll
            for (int r = 0; r < 4; ++r) {
                floatx4 o = {0.f, 0.f, 0.f, 0.f};
                o = MFMA(sb0, pf[r][0], o);
                o = MFMA(sb1, pf[r][1], o);
                *(floatx4*)&op[(r * 16 + m) * 64 + c2 * 16 + q * 4] = o;
            }
        }

        if (!hasnext) break;
        n = nn;
        xp += stride * 4096;
    }
#undef LDCHUNK
#undef PHASE_A
}

extern "C" void kernel_launch(void* const* d_in, const int* in_sizes, int n_in,
                              void* d_out, int out_size, void* d_ws, size_t ws_size,
                              hipStream_t stream) {
    const float* x    = (const float*)d_in[0];
    const float* u_l  = (const float*)d_in[1];
    const float* v_l  = (const float*)d_in[2];
    const float* dg_l = (const float*)d_in[3];
    const float* u_r  = (const float*)d_in[4];
    const float* v_r  = (const float*)d_in[5];
    const float* dg_r = (const float*)d_in[6];
    const float* dsc  = (const float*)d_in[7];
    float* out = (float*)d_out;
    short* ws  = (short*)d_ws;   // [0..4095]=m_left^T bf16, [4096..8191]=m_right^T bf16

    int N = in_sizes[0] / 4096;  // 8192 matrices of 64x64

    hipLaunchKernelGGL(k_prep, dim3(2), dim3(256), 0, stream,
                       u_l, v_l, dg_l, u_r, v_r, dg_r, ws);
    // 768 blocks = 3/CU (LDS-limited), all resident; waves stride the stream
    hipLaunchKernelGGL(k_main, dim3(768), dim3(256), 0, stream,
                       x, dsc, ws, ws + 4096, out, N);
}

// Round 5
// 270.215 us; speedup vs baseline: 1.0497x; 1.0497x over previous
//
#include <hip/hip_runtime.h>
#include <hip/hip_bf16.h>

typedef __attribute__((ext_vector_type(8))) short short8;   // 8 bf16 = 4 VGPRs (MFMA A/B frag)
typedef __attribute__((ext_vector_type(4))) short short4v;  // 4 bf16 = 8 B
typedef __attribute__((ext_vector_type(4))) float floatx4;  // MFMA C/D frag

#define MFMA(a, b, c) __builtin_amdgcn_mfma_f32_16x16x32_bf16((a), (b), (c), 0, 0, 0)

// fp32 -> bf16, round-to-nearest-even (bit trick; inputs are finite)
__device__ __forceinline__ short f2bf(float f) {
    unsigned u = __float_as_uint(f);
    u += 0x7fffu + ((u >> 16) & 1u);
    return (short)(u >> 16);
}

__device__ __forceinline__ short8 pack_bf16(floatx4 a, floatx4 b) {
    short8 r;
    r[0] = f2bf(a.x); r[1] = f2bf(a.y); r[2] = f2bf(a.z); r[3] = f2bf(a.w);
    r[4] = f2bf(b.x); r[5] = f2bf(b.y); r[6] = f2bf(b.z); r[7] = f2bf(b.w);
    return r;
}

// ---------------------------------------------------------------------------
// Cayley via Neumann/Horner series on one block (256 threads, 4 waves).
// (unchanged — negligible runtime)
// ---------------------------------------------------------------------------
__device__ void cayley64(const float* __restrict__ X, const float* __restrict__ dg,
                         short* outArr, int mode,
                         short* Brow, float* Bcol, short* T0, short* T1, int tid)
{
    int i0 = (tid * 16) >> 6;
    int j0 = (tid * 16) & 63;
#pragma unroll
    for (int s = 0; s < 16; ++s) {
        int i = i0, j = j0 + s;
        float b = 0.f;
        if (i > j)      b =  0.5f * X[i * 64 + j];
        else if (i < j) b = -0.5f * X[j * 64 + i];
        Brow[i * 72 + j] = f2bf(b);
        Bcol[j * 68 + i] = b;
        T0[j * 72 + i]   = f2bf(b);
    }
    __syncthreads();

    int lane = tid & 63, w = tid >> 6, m = lane & 15, q = lane >> 4;
    int arow = (w * 16 + m) * 72;
    short8 a0 = *(const short8*)&Brow[arow + q * 8];
    short8 a1 = *(const short8*)&Brow[arow + 32 + q * 8];

    short* Tbuf[2] = {T0, T1};
    int cur = 0;
    const int NSTEP = 6;
    for (int step = 0; step < NSTEP; ++step) {
        bool last = (step == NSTEP - 1);
        short* Tr = Tbuf[cur];
        short* Tw = Tbuf[cur ^ 1];
#pragma unroll
        for (int c = 0; c < 4; ++c) {
            int coff = c * 16 + m;
            short8 b0 = *(const short8*)&Tr[coff * 72 + q * 8];
            short8 b1 = *(const short8*)&Tr[coff * 72 + 32 + q * 8];
            floatx4 acc = {0.f, 0.f, 0.f, 0.f};
            acc = MFMA(a0, b0, acc);
            acc = MFMA(a1, b1, acc);
            int row0 = w * 16 + q * 4;
            floatx4 badd = *(const floatx4*)&Bcol[coff * 68 + row0];
            floatx4 t = badd + acc;                 // T_new = B + B*T_old
            if (!last) {
                short4v pk = { f2bf(t.x), f2bf(t.y), f2bf(t.z), f2bf(t.w) };
                *(short4v*)&Tw[coff * 72 + row0] = pk;
            } else {
                int col = coff;
                floatx4 cv;
                cv.x = ((row0 + 0) == col ? 1.f : 0.f) + 2.f * t.x;
                cv.y = ((row0 + 1) == col ? 1.f : 0.f) + 2.f * t.y;
                cv.z = ((row0 + 2) == col ? 1.f : 0.f) + 2.f * t.z;
                cv.w = ((row0 + 3) == col ? 1.f : 0.f) + 2.f * t.w;
                if (mode == 0) {
                    outArr[(row0 + 0) * 72 + col] = f2bf(cv.x);
                    outArr[(row0 + 1) * 72 + col] = f2bf(cv.y);
                    outArr[(row0 + 2) * 72 + col] = f2bf(cv.z);
                    outArr[(row0 + 3) * 72 + col] = f2bf(cv.w);
                } else {
                    floatx4 dv = *(const floatx4*)&dg[row0];
                    short4v pk = { f2bf(cv.x * dv.x), f2bf(cv.y * dv.y),
                                   f2bf(cv.z * dv.z), f2bf(cv.w * dv.w) };
                    *(short4v*)&outArr[col * 72 + row0] = pk;
                }
            }
        }
        __syncthreads();
        cur ^= 1;
    }
}

// ---------------------------------------------------------------------------
// k_prep: 2 blocks. Block 0 -> m_left^T, block 1 -> m_right^T (bf16 row-major)
// ---------------------------------------------------------------------------
__global__ __launch_bounds__(256) void k_prep(
        const float* __restrict__ u_l, const float* __restrict__ v_l, const float* __restrict__ dg_l,
        const float* __restrict__ u_r, const float* __restrict__ v_r, const float* __restrict__ dg_r,
        short* __restrict__ wsOut)
{
    __shared__ __align__(16) short Brow[64 * 72];
    __shared__ __align__(16) float Bcol[64 * 68];
    __shared__ __align__(16) short T0[64 * 72];
    __shared__ __align__(16) short T1[64 * 72];
    __shared__ __align__(16) short CvA[64 * 72];
    __shared__ __align__(16) short CuB[64 * 72];

    int tid = threadIdx.x;
    const float* U  = (blockIdx.x == 0) ? u_l  : u_r;
    const float* V  = (blockIdx.x == 0) ? v_l  : v_r;
    const float* DG = (blockIdx.x == 0) ? dg_l : dg_r;
    short* outT = wsOut + blockIdx.x * 4096;

    cayley64(V, DG, CvA, 1, Brow, Bcol, T0, T1, tid);
    __syncthreads();
    cayley64(U, DG, CuB, 0, Brow, Bcol, T0, T1, tid);
    __syncthreads();

    int lane = tid & 63, w = tid >> 6, m = lane & 15, q = lane >> 4;
    int arow = (w * 16 + m) * 72;
    short8 a0 = *(const short8*)&CvA[arow + q * 8];
    short8 a1 = *(const short8*)&CvA[arow + 32 + q * 8];
#pragma unroll
    for (int c = 0; c < 4; ++c) {
        short8 b0 = *(const short8*)&CuB[(c * 16 + m) * 72 + q * 8];
        short8 b1 = *(const short8*)&CuB[(c * 16 + m) * 72 + 32 + q * 8];
        floatx4 acc = {0.f, 0.f, 0.f, 0.f};
        acc = MFMA(a0, b0, acc);
        acc = MFMA(a1, b1, acc);
        int row0 = w * 16 + q * 4, col = c * 16 + m;
        outT[(row0 + 0) * 64 + col] = f2bf(acc.x);
        outT[(row0 + 1) * 64 + col] = f2bf(acc.y);
        outT[(row0 + 2) * 64 + col] = f2bf(acc.z);
        outT[(row0 + 3) * 64 + col] = f2bf(acc.w);
    }
}

// ---------------------------------------------------------------------------
// k_main v8: out_n = P @ (x_n * dscale) @ Q
//   STORE-DECOUPLED full-matrix pipeline (the one cell the R1-R4 scan left
//   unexplored).  vmcnt retires IN ORDER, so in v7 half the chunk-waits
//   could not complete until the previous matrix's 16 stores drained.
//   v8 issue order per matrix i:
//     PA(i)   : 4 chunk-waits (all x(i) regs consumed)
//     ISSUE   : all 16 loads of matrix i+1  (before any store!)
//     PB(i)   : S^T reads + MFMA + stores (stores are YOUNGER than every
//               load we will ever wait on -> no load-wait drains stores;
//               stores get a full matrix-phase to retire in background)
//   Full matrix in registers: 16 named floatx4 (64 VGPR) -> no scratch.
//   PB computes c2-PAIRS and stores the two 64B halves of each 128B line
//   back-to-back (fixes v7's 144MB write amplification -> 131MB).
//   VGPR ~200 -> 2 waves/SIMD (8/CU).  Numerics bit-identical to v7.
// ---------------------------------------------------------------------------
__global__ __launch_bounds__(256, 2) void k_main(
        const float* __restrict__ x, const float* __restrict__ dsc,
        const short* __restrict__ mLT, const short* __restrict__ mRT,
        float* __restrict__ out, int N)
{
    __shared__ __align__(16) char  STb[4][8192];   // per-wave swizzled S^T
    __shared__ __align__(16) float dsl[64 * 68];   // dscale, +4 float row pad

    const int tid = threadIdx.x;
    const int w = tid >> 6, lane = tid & 63, m = lane & 15, q = lane >> 4;
    const int s8 = m & 7;
    char* st = STb[w];

    // ---- stage dscale to LDS (once; only barrier in the kernel)
    {
        int row = tid >> 2, c4 = (tid & 3) * 16;
        const float* g = dsc + row * 64 + c4;
        float* l = dsl + row * 68 + c4;
        *(floatx4*)&l[0]  = *(const floatx4*)&g[0];
        *(floatx4*)&l[4]  = *(const floatx4*)&g[4];
        *(floatx4*)&l[8]  = *(const floatx4*)&g[8];
        *(floatx4*)&l[12] = *(const floatx4*)&g[12];
    }

    // P-row frags (B-operand of P^T in phase B) and Q^T frags
    short8 pf[4][2], qf[4][2];
#pragma unroll
    for (int r = 0; r < 4; ++r) {
        pf[r][0] = *(const short8*)&mLT[(r * 16 + m) * 64 + q * 8];
        pf[r][1] = *(const short8*)&mLT[(r * 16 + m) * 64 + 32 + q * 8];
        qf[r][0] = *(const short8*)&mRT[(r * 16 + m) * 64 + q * 8];
        qf[r][1] = *(const short8*)&mRT[(r * 16 + m) * 64 + 32 + q * 8];
    }
    __syncthreads();

    const long stride = (long)gridDim.x * 4;        // matrices per generation
    const long wgid = (long)blockIdx.x * 4 + w;
    if (wgid >= N) return;

    const int loff = m * 64 + q * 8;                // lane offset within chunk

// issue the 16 chunk loads of one matrix into the named register file
#define LD16(p) do {                                                     \
        const float* b0_ = (p);                                          \
        x00 = *(const floatx4*)&b0_[0];    x01 = *(const floatx4*)&b0_[4];    \
        x02 = *(const floatx4*)&b0_[32];   x03 = *(const floatx4*)&b0_[36];   \
        const float* b1_ = (p) + 1024;                                   \
        x10 = *(const floatx4*)&b1_[0];    x11 = *(const floatx4*)&b1_[4];    \
        x12 = *(const floatx4*)&b1_[32];   x13 = *(const floatx4*)&b1_[36];   \
        const float* b2_ = (p) + 2048;                                   \
        x20 = *(const floatx4*)&b2_[0];    x21 = *(const floatx4*)&b2_[4];    \
        x22 = *(const floatx4*)&b2_[32];   x23 = *(const floatx4*)&b2_[36];   \
        const float* b3_ = (p) + 3072;                                   \
        x30 = *(const floatx4*)&b3_[0];    x31 = *(const floatx4*)&b3_[4];    \
        x32 = *(const floatx4*)&b3_[32];   x33 = *(const floatx4*)&b3_[36];   \
        asm volatile("" ::: "memory");                                   \
    } while (0)

// phase A for row-tile rt using chunk regs: S row-tile -> swizzled S^T slice
#define PHASE_A(rt, r0, r1, r2, r3) do {                                      \
        const float* dp_ = &dsl[((rt) * 16 + m) * 68 + q * 8];                \
        floatx4 d0_ = *(const floatx4*)&dp_[0];                               \
        floatx4 d1_ = *(const floatx4*)&dp_[4];                               \
        floatx4 d2_ = *(const floatx4*)&dp_[32];                              \
        floatx4 d3_ = *(const floatx4*)&dp_[36];                              \
        short8 a0_ = pack_bf16(r0 * d0_, r1 * d1_);   /* k 0..31  */          \
        short8 a1_ = pack_bf16(r2 * d2_, r3 * d3_);   /* k 32..63 */          \
        _Pragma("unroll")                                                     \
        for (int c_ = 0; c_ < 4; ++c_) {                                      \
            floatx4 s_ = {0.f, 0.f, 0.f, 0.f};                                \
            s_ = MFMA(a0_, qf[c_][0], s_);                                    \
            s_ = MFMA(a1_, qf[c_][1], s_);                                    \
            short4v pk_ = { f2bf(s_.x), f2bf(s_.y), f2bf(s_.z), f2bf(s_.w) }; \
            *(short4v*)&st[(c_ * 16 + m) * 128 +                              \
                (((2 * (rt) + (q >> 1)) ^ s8) << 4) + (q & 1) * 8] = pk_;     \
        }                                                                     \
    } while (0)

    long n = wgid;
    const float* xp = x + n * 4096 + loff;

    floatx4 x00, x01, x02, x03, x10, x11, x12, x13;
    floatx4 x20, x21, x22, x23, x30, x31, x32, x33;

    // prologue: full matrix 0 in flight (16 dwordx4 = 4KB/wave)
    LD16(xp);

    for (;;) {
        const long nn = n + stride;
        const bool hasnext = (nn < N);              // wave-uniform

        // ---- phase A: consume all 16 chunk regs (the only load-waits).
        // FIFO at each wait: [remaining loads(i)] [stores(i-1)] -- stores are
        // YOUNGER than every load we wait on, so they are never drained here.
        PHASE_A(0, x00, x01, x02, x03);
        PHASE_A(1, x10, x11, x12, x13);
        PHASE_A(2, x20, x21, x22, x23);
        PHASE_A(3, x30, x31, x32, x33);
        asm volatile("" ::: "memory");

        // ---- issue ALL of matrix i+1's loads BEFORE any store of matrix i
        const float* xnp = xp + (size_t)stride * 4096;
        if (hasnext) LD16(xnp);
        asm volatile("" ::: "memory");

        // ---- phase B: O^T = S^T @ P^T (operand-swapped).  c2-pairs so the
        // two 64B halves of each 128B out-line are stored back-to-back.
        float* op = out + (size_t)n * 4096;
#pragma unroll
        for (int cp = 0; cp < 2; ++cp) {
            const int rowbA = ((2 * cp) * 16 + m) * 128;
            const int rowbB = ((2 * cp + 1) * 16 + m) * 128;
            short8 sbA0 = *(const short8*)&st[rowbA + ((q       ^ s8) << 4)];
            short8 sbA1 = *(const short8*)&st[rowbA + (((4 + q) ^ s8) << 4)];
            short8 sbB0 = *(const short8*)&st[rowbB + ((q       ^ s8) << 4)];
            short8 sbB1 = *(const short8*)&st[rowbB + (((4 + q) ^ s8) << 4)];
#pragma unroll
            for (int r = 0; r < 4; ++r) {
                floatx4 oa = {0.f, 0.f, 0.f, 0.f};
                floatx4 ob = {0.f, 0.f, 0.f, 0.f};
                oa = MFMA(sbA0, pf[r][0], oa);
                oa = MFMA(sbA1, pf[r][1], oa);
                ob = MFMA(sbB0, pf[r][0], ob);
                ob = MFMA(sbB1, pf[r][1], ob);
                float* rp = &op[(r * 16 + m) * 64];
                *(floatx4*)&rp[(2 * cp) * 16 + q * 4]     = oa;  // bytes [cp*128 + q*16 .. )
                *(floatx4*)&rp[(2 * cp + 1) * 16 + q * 4] = ob;  // completes the 128B line
            }
        }

        if (!hasnext) break;
        n = nn;
        xp = xnp;
    }
#undef LD16
#undef PHASE_A
}

extern "C" void kernel_launch(void* const* d_in, const int* in_sizes, int n_in,
                              void* d_out, int out_size, void* d_ws, size_t ws_size,
                              hipStream_t stream) {
    const float* x    = (const float*)d_in[0];
    const float* u_l  = (const float*)d_in[1];
    const float* v_l  = (const float*)d_in[2];
    const float* dg_l = (const float*)d_in[3];
    const float* u_r  = (const float*)d_in[4];
    const float* v_r  = (const float*)d_in[5];
    const float* dg_r = (const float*)d_in[6];
    const float* dsc  = (const float*)d_in[7];
    float* out = (float*)d_out;
    short* ws  = (short*)d_ws;   // [0..4095]=m_left^T bf16, [4096..8191]=m_right^T bf16

    int N = in_sizes[0] / 4096;  // 8192 matrices of 64x64

    hipLaunchKernelGGL(k_prep, dim3(2), dim3(256), 0, stream,
                       u_l, v_l, dg_l, u_r, v_r, dg_r, ws);
    // 512 blocks = 2/CU resident (VGPR-banded at 2 waves/SIMD); waves stride
    hipLaunchKernelGGL(k_main, dim3(512), dim3(256), 0, stream,
                       x, dsc, ws, ws + 4096, out, N);
}